// Round 23
// baseline (188.740 us; speedup 1.0000x reference)
//
#include <hip/hip_runtime.h>
#include <math.h>

#define NPTS 8192
#define NB   4
#define KNN  16
#define NC   64
#define NQ   (NB * NPTS)   // 32768 total queries
#define ECAP 20            // per-(wave,query) packed-entry capacity (E~2.7)
#define ILCAP 66           // per-query decoded survivor idx capacity (E~22)

// bit-exact float transport over the scalar pipe (v_readlane_b32 -> SGPR)
__device__ __forceinline__ float readlane_f(float v, int l) {
    return __int_as_float(__builtin_amdgcn_readlane(__float_as_int(v), l));
}

// ---------------------------------------------------------------------------
// prep — unchanged (r21 validated): transposed ownership, lane = channel o.
//  phase 0 (source pts): cand[b][m]=(x,y,z,|p|^2); GF[b][m][o]=(Gk,F2)
//  phase 1 (center pts): CF[b][n][o]=(Gc+bg, F1+bf)
// ---------------------------------------------------------------------------
__global__ __launch_bounds__(64) void prep_kernel(
    const float* __restrict__ xyz, const float* __restrict__ xyz_s,
    const float* __restrict__ fea, const float* __restrict__ fea_s,
    const float* __restrict__ Wg,  const float* __restrict__ bg,
    const float* __restrict__ Wf,  const float* __restrict__ bf,
    float4* __restrict__ cand, float2* __restrict__ GF, float2* __restrict__ CF)
{
    int o     = threadIdx.x;                 // this lane's output channel
    int phase = blockIdx.x & 1;
    int g     = (blockIdx.x >> 1) * 64;      // first point of tile
    int b     = g >> 13, p0 = g & (NPTS - 1);

    const float* P = phase ? xyz : xyz_s;
    const float* F = phase ? fea : fea_s;

    if (!phase) {
        float x = xyz_s[(b * 3 + 0) * NPTS + p0 + o];
        float y = xyz_s[(b * 3 + 1) * NPTS + p0 + o];
        float z = xyz_s[(b * 3 + 2) * NPTS + p0 + o];
        cand[b * NPTS + p0 + o] = make_float4(x, y, z, x * x + y * y + z * z);
    }

    const float* wrow = Wf + o * 128 + (phase ? 0 : 64);
    float gwx = phase ? (Wg[o * 10 + 1] + Wg[o * 10 + 7])
                      : (Wg[o * 10 + 4] - Wg[o * 10 + 7]);
    float gwy = phase ? (Wg[o * 10 + 2] + Wg[o * 10 + 8])
                      : (Wg[o * 10 + 5] - Wg[o * 10 + 8]);
    float gwz = phase ? (Wg[o * 10 + 3] + Wg[o * 10 + 9])
                      : (Wg[o * 10 + 6] - Wg[o * 10 + 9]);
    float bgo = phase ? bg[o] : 0.f;
    float bfo = phase ? bf[o] : 0.f;

    float acc[64];
    #pragma unroll
    for (int p = 0; p < 64; p++) acc[p] = 0.f;

    for (int c = 0; c < 64; c++) {
        float wv = wrow[c];
        const float4* fr =
            (const float4*)(F + (size_t)(b * NC + c) * NPTS + p0);
        #pragma unroll
        for (int p4 = 0; p4 < 16; p4++) {
            float4 v = fr[p4];                        // wave-uniform -> s_load
            acc[p4 * 4 + 0] = fmaf(wv, v.x, acc[p4 * 4 + 0]);
            acc[p4 * 4 + 1] = fmaf(wv, v.y, acc[p4 * 4 + 1]);
            acc[p4 * 4 + 2] = fmaf(wv, v.z, acc[p4 * 4 + 2]);
            acc[p4 * 4 + 3] = fmaf(wv, v.w, acc[p4 * 4 + 3]);
        }
    }

    float2* O = (phase ? CF : GF) + ((size_t)(b * NPTS + p0)) * NC + o;
    for (int p = 0; p < 64; p++) {
        float x = P[(b * 3 + 0) * NPTS + p0 + p];
        float y = P[(b * 3 + 1) * NPTS + p0 + p];
        float z = P[(b * 3 + 2) * NPTS + p0 + p];
        float geo = fmaf(gwx, x, fmaf(gwy, y, gwz * z)) + bgo;
        O[(size_t)p * NC] = make_float2(geo, acc[p] + bfo);
    }
}

// ---------------------------------------------------------------------------
// knn_fused7 — r22 structure with the readlane TYPE BUG fixed.
// [r22 post-mortem: __builtin_amdgcn_readlane(float, int) implicitly
//  CONVERTED the float coordinate to int (numeric truncation!) — A/B scored
//  against integer-truncated queries while S rescored with correct coords ->
//  bad tau -> missing neighbors (absmax 7.9). Fix: bitcast transport
//  (readlane_f). Architecture unchanged: query operands delivered via the
//  scalar pipe (v_readlane -> SGPR), zero LDS traffic in A/B score loops.]
// Wave w owns cands [1024w,1024(w+1)); lane owns c[s]=cb[w*1024+s*64+lane].
//  A: full 16-slot dual-chain lane max -> shfl_xor(1,2,4) -> 64 submaxima.
//  T: tau = 16th largest of 64 submaxima -> tauL[qq]; >=16 witnesses.
//  B: branch-free u16 mask filter, ONE ballot/query, packed entries.
//  S: decode -> idx list (dead mxs row) -> batch-4 gather + u64 insert.
// Grid: NQ/64 = 512 blocks x 512 threads.
// ---------------------------------------------------------------------------
__global__ __launch_bounds__(512, 4) void knn_fused7(
    const float4* __restrict__ cand, const float* __restrict__ xyz,
    int* __restrict__ idxout)
{
    __shared__ float  mxs[64][ILCAP];        // A/T: submaxima; S: idx list
    __shared__ float  tauL[64];
    __shared__ unsigned int  el[8][64][ECAP];
    __shared__ unsigned char ecnt[8][64];

    int tid = threadIdx.x;
    int lane = tid & 63, w = tid >> 6;       // w in 0..7
    int bid = blockIdx.x;
    int b = bid >> 7;                        // 128 blocks per batch
    int qb = (bid & 127) * 64;

    // lane l holds query qb+l's scaled coords in registers (no LDS)
    float mqx = 2.f * xyz[(b * 3 + 0) * NPTS + qb + lane];
    float mqy = 2.f * xyz[(b * 3 + 1) * NPTS + qb + lane];
    float mqz = 2.f * xyz[(b * 3 + 2) * NPTS + qb + lane];

    const float4* cb = cand + b * NPTS;
    int cbase = (w << 10) + lane;            // lane's cands: cbase + s*64
    float4 c[16];
    #pragma unroll
    for (int s = 0; s < 16; s++) c[s] = cb[cbase + (s << 6)];
    // residency force (r15-validated): compiler cannot re-load from memory
    #pragma unroll
    for (int s = 0; s < 16; s++)
        asm volatile("" : "+v"(c[s].x), "+v"(c[s].y), "+v"(c[s].z), "+v"(c[s].w));

    // ---- A: 64 submaxima per query (query operands via v_readlane/SGPR) --
    for (int qi = 0; qi < 64; ++qi) {
        float ax = readlane_f(mqx, qi);
        float ay = readlane_f(mqy, qi);
        float az = readlane_f(mqz, qi);
        float M0 = -3.0e38f, M1 = -3.0e38f;
        #pragma unroll
        for (int s = 0; s < 16; s += 2) {
            float sc0 = fmaf(c[s].x, ax, fmaf(c[s].y, ay,
                        fmaf(c[s].z, az, -c[s].w)));
            float sc1 = fmaf(c[s+1].x, ax, fmaf(c[s+1].y, ay,
                        fmaf(c[s+1].z, az, -c[s+1].w)));
            M0 = fmaxf(M0, sc0);
            M1 = fmaxf(M1, sc1);
        }
        float gmx = fmaxf(M0, M1);
        gmx = fmaxf(gmx, __shfl_xor(gmx, 1));
        gmx = fmaxf(gmx, __shfl_xor(gmx, 2));
        gmx = fmaxf(gmx, __shfl_xor(gmx, 4));   // 8-lane group max
        if ((lane & 7) == 0) mxs[qi][(w << 3) + (lane >> 3)] = gmx;
    }
    __syncthreads();

    // ---- T: tau = 16th largest of 64 submaxima -> tauL[qq] ----
    for (int qq = w * 8; qq < w * 8 + 8; ++qq) {
        float v = mxs[qq][lane];
        #pragma unroll
        for (int k = 2; k <= 64; k <<= 1) {
            #pragma unroll
            for (int j = k >> 1; j > 0; j >>= 1) {
                float o = __shfl_xor(v, j);
                bool up = ((lane & k) == 0);
                bool lower = ((lane & j) == 0);
                v = (up == lower) ? fminf(v, o) : fmaxf(v, o);
            }
        }
        float t = __shfl(v, 48);             // 16th largest (all lanes)
        if (lane == 0) tauL[qq] = t;
    }
    __syncthreads();

    float mytau = tauL[lane];                // one LDS read per lane, cached

    // ---- B: branch-free mask filter; query+tau via readlane/SGPR ----
    unsigned long long lmask = (1ull << lane) - 1ull;
    for (int qi = 0; qi < 64; ++qi) {
        float ax  = readlane_f(mqx, qi);
        float ay  = readlane_f(mqy, qi);
        float az  = readlane_f(mqz, qi);
        float tau = readlane_f(mytau, qi);
        unsigned msk = 0;
        #pragma unroll
        for (int s = 0; s < 16; s++) {
            float sc = fmaf(c[s].x, ax, fmaf(c[s].y, ay,
                       fmaf(c[s].z, az, -c[s].w)));
            msk |= (sc >= tau) ? (1u << s) : 0u;
        }
        unsigned long long m = __ballot(msk != 0u);
        if (msk) {
            unsigned pos = (unsigned)__popcll(m & lmask);
            if (pos < ECAP)
                el[w][qi][pos] = ((unsigned)lane << 16) | msk;
        }
        if (lane == 0) {
            unsigned tot = (unsigned)__popcll(m);
            ecnt[w][qi] = (unsigned char)(tot < ECAP ? tot : ECAP);
        }
    }
    __syncthreads();

    // ---- S: decode entries -> idx list (reuse mxs row), then top-16 ----
    // wave 0, lane qi: myqt registers already hold query qb+qi's coords.
    if (tid < 64) {
        int qi = tid;
        unsigned* il = (unsigned*)&mxs[qi][0];   // ILCAP u32 slots
        int cnt = 0;
        for (int w2 = 0; w2 < 8; w2++) {
            int cn = ecnt[w2][qi];
            for (int j = 0; j < cn; j++) {
                unsigned e = el[w2][qi][j];
                int base = (w2 << 10) + (int)(e >> 16);
                unsigned mk = e & 0xFFFFu;
                while (mk) {
                    int s = __builtin_ctz(mk);
                    mk &= mk - 1u;
                    if (cnt < ILCAP) il[cnt++] = (unsigned)(base + (s << 6));
                }
            }
        }

        unsigned long long s16[KNN];
        #pragma unroll
        for (int j = 0; j < KNN; j++) s16[j] = 0ull;

        for (int j0 = 0; j0 < cnt; j0 += 4) {
            int li[4];
            float4 cd[4];
            #pragma unroll
            for (int t = 0; t < 4; t++) {
                int j = j0 + t;
                li[t] = (j < cnt) ? (int)il[j] : -1;
            }
            #pragma unroll
            for (int t = 0; t < 4; t++)
                if (li[t] >= 0) cd[t] = cb[li[t]];
            #pragma unroll
            for (int t = 0; t < 4; t++) {
                if (li[t] < 0) continue;
                float sc = fmaf(cd[t].x, mqx, fmaf(cd[t].y, mqy,
                           fmaf(cd[t].z, mqz, -cd[t].w)));
                unsigned u = __float_as_uint(sc);
                u ^= (unsigned)((int)u >> 31) | 0x80000000u;
                unsigned long long key =
                    ((unsigned long long)u << 32) | (unsigned)(8191 - li[t]);
                if (key > s16[0]) {
                    bool cj = true;
                    #pragma unroll
                    for (int t2 = 0; t2 < KNN; t2++) {
                        bool cn2 = (t2 < KNN - 1) ? (key > s16[t2 + 1]) : false;
                        unsigned long long fv = cj ? key : s16[t2];
                        s16[t2] = cn2 ? s16[t2 + 1] : fv;
                        cj = cn2;
                    }
                }
            }
        }
        int* op = idxout + (((size_t)(b * NPTS + qb + qi)) << 4);
        #pragma unroll
        for (int j = 0; j < KNN; j++)
            op[j] = 8191 - (int)(s16[j] & 0xFFFFFFFFull);
    }
}

// ---------------------------------------------------------------------------
// fuse — unchanged (r20 validated): explicit register-batch gathers.
// out[b][o][n] = max_k relu(CF.x + wd*d + GF.x) * relu(CF.y + GF.y)
// ---------------------------------------------------------------------------
__global__ __launch_bounds__(256) void fuse_kernel(
    const float* __restrict__ xyz, const float* __restrict__ Wg,
    const float4* __restrict__ cand, const float2* __restrict__ GF,
    const float2* __restrict__ CF, const int* __restrict__ idxb,
    float* __restrict__ out)
{
    __shared__ float tile[16 * 65];
    int tid = threadIdx.x;
    int o = tid & 63, w = tid >> 6;
    int b = blockIdx.x >> 9;
    int nt = (blockIdx.x & 511) << 4;
    float wd = Wg[o * 10];

    const float4* cb = cand + b * NPTS;
    const float2* gb = GF + (size_t)b * NPTS * NC;

    for (int i = 0; i < 4; i++) {
        int q = nt + w * 4 + i;
        size_t qb = (size_t)(b * NPTS + q);
        float qx = xyz[(b * 3 + 0) * NPTS + q];
        float qy = xyz[(b * 3 + 1) * NPTS + q];
        float qz = xyz[(b * 3 + 2) * NPTS + q];
        float2 cf = CF[qb * NC + o];
        const int* ip = idxb + qb * KNN;

        int mi[16];
        #pragma unroll
        for (int kk = 0; kk < 16; kk++) mi[kk] = ip[kk];   // broadcast loads

        float r = 0.f;
        #pragma unroll
        for (int h = 0; h < 2; h++) {
            float4 cd[8];
            float2 gf[8];
            #pragma unroll
            for (int t = 0; t < 8; t++) cd[t] = cb[mi[h * 8 + t]];
            #pragma unroll
            for (int t = 0; t < 8; t++)
                gf[t] = gb[(size_t)mi[h * 8 + t] * NC + o];
            #pragma unroll
            for (int t = 0; t < 8; t++) {
                float dx = qx - cd[t].x, dy = qy - cd[t].y, dz = qz - cd[t].z;
                float d = sqrtf(fmaf(dx, dx, fmaf(dy, dy, dz * dz)));
                float gpre = cf.x + fmaf(wd, d, gf[t].x);
                float fpre = cf.y + gf[t].y;
                r = fmaxf(r, fmaxf(gpre, 0.f) * fmaxf(fpre, 0.f));
            }
        }
        tile[(w * 4 + i) * 65 + o] = r;
    }
    __syncthreads();
    int row = tid >> 2, cg = (tid & 3) * 4;
    float* orow = out + (size_t)(b * NC + row) * NPTS + nt + cg;
    #pragma unroll
    for (int j = 0; j < 4; j++) orow[j] = tile[(cg + j) * 65 + row];
}

extern "C" void kernel_launch(void* const* d_in, const int* in_sizes, int n_in,
                              void* d_out, int out_size, void* d_ws, size_t ws_size,
                              hipStream_t stream) {
    const float* xyz   = (const float*)d_in[0];
    const float* xyz_s = (const float*)d_in[1];
    const float* fea   = (const float*)d_in[2];
    const float* fea_s = (const float*)d_in[3];
    const float* Wg    = (const float*)d_in[4];
    const float* bg    = (const float*)d_in[5];
    const float* Wf    = (const float*)d_in[6];
    const float* bf    = (const float*)d_in[7];
    float* out = (float*)d_out;

    char* ws = (char*)d_ws;
    float4* cand = (float4*)ws;                 ws += (size_t)NQ * 16;      // 512 KB
    float2* GF   = (float2*)ws;                 ws += (size_t)NQ * NC * 8;  // 16.8 MB
    float2* CF   = (float2*)ws;                 ws += (size_t)NQ * NC * 8;  // 16.8 MB
    int*    idxb = (int*)ws;                                                // 2 MB

    // prep: transposed ownership, 64 points / 64 threads, 2 phases
    prep_kernel<<<(NQ / 64) * 2, 64, 0, stream>>>(
        xyz, xyz_s, fea, fea_s, Wg, bg, Wf, bf, cand, GF, CF);
    knn_fused7<<<NQ / 64, 512, 0, stream>>>(cand, xyz, idxb);
    fuse_kernel<<<NB * (NPTS / 16), 256, 0, stream>>>(
        xyz, Wg, cand, GF, CF, idxb, out);
}

// Round 24
// 178.914 us; speedup vs baseline: 1.0549x; 1.0549x over previous
//
#include <hip/hip_runtime.h>
#include <math.h>

#define NPTS 8192
#define NB   4
#define KNN  16
#define NC   64
#define NQ   (NB * NPTS)   // 32768 total queries
#define ECAP 20            // per-(wave,query) packed-entry capacity (E~2.7)
#define ILCAP 66           // per-query decoded survivor idx capacity (E~22)

// ---------------------------------------------------------------------------
// prep — r21 validated: transposed ownership, lane = output channel o.
//  phase 0 (source pts): cand[b][m]=(x,y,z,|p|^2); GF[b][m][o]=(Gk,F2)
//  phase 1 (center pts): CF[b][n][o]=(Gc+bg, F1+bf)
// Weights per-lane (L1), fea reads wave-uniform (s_load), stores coalesced.
// ---------------------------------------------------------------------------
__global__ __launch_bounds__(64) void prep_kernel(
    const float* __restrict__ xyz, const float* __restrict__ xyz_s,
    const float* __restrict__ fea, const float* __restrict__ fea_s,
    const float* __restrict__ Wg,  const float* __restrict__ bg,
    const float* __restrict__ Wf,  const float* __restrict__ bf,
    float4* __restrict__ cand, float2* __restrict__ GF, float2* __restrict__ CF)
{
    int o     = threadIdx.x;                 // this lane's output channel
    int phase = blockIdx.x & 1;
    int g     = (blockIdx.x >> 1) * 64;      // first point of tile
    int b     = g >> 13, p0 = g & (NPTS - 1);

    const float* P = phase ? xyz : xyz_s;
    const float* F = phase ? fea : fea_s;

    if (!phase) {
        float x = xyz_s[(b * 3 + 0) * NPTS + p0 + o];
        float y = xyz_s[(b * 3 + 1) * NPTS + p0 + o];
        float z = xyz_s[(b * 3 + 2) * NPTS + p0 + o];
        cand[b * NPTS + p0 + o] = make_float4(x, y, z, x * x + y * y + z * z);
    }

    const float* wrow = Wf + o * 128 + (phase ? 0 : 64);
    float gwx = phase ? (Wg[o * 10 + 1] + Wg[o * 10 + 7])
                      : (Wg[o * 10 + 4] - Wg[o * 10 + 7]);
    float gwy = phase ? (Wg[o * 10 + 2] + Wg[o * 10 + 8])
                      : (Wg[o * 10 + 5] - Wg[o * 10 + 8]);
    float gwz = phase ? (Wg[o * 10 + 3] + Wg[o * 10 + 9])
                      : (Wg[o * 10 + 6] - Wg[o * 10 + 9]);
    float bgo = phase ? bg[o] : 0.f;
    float bfo = phase ? bf[o] : 0.f;

    float acc[64];
    #pragma unroll
    for (int p = 0; p < 64; p++) acc[p] = 0.f;

    for (int c = 0; c < 64; c++) {
        float wv = wrow[c];
        const float4* fr =
            (const float4*)(F + (size_t)(b * NC + c) * NPTS + p0);
        #pragma unroll
        for (int p4 = 0; p4 < 16; p4++) {
            float4 v = fr[p4];                        // wave-uniform -> s_load
            acc[p4 * 4 + 0] = fmaf(wv, v.x, acc[p4 * 4 + 0]);
            acc[p4 * 4 + 1] = fmaf(wv, v.y, acc[p4 * 4 + 1]);
            acc[p4 * 4 + 2] = fmaf(wv, v.z, acc[p4 * 4 + 2]);
            acc[p4 * 4 + 3] = fmaf(wv, v.w, acc[p4 * 4 + 3]);
        }
    }

    float2* O = (phase ? CF : GF) + ((size_t)(b * NPTS + p0)) * NC + o;
    for (int p = 0; p < 64; p++) {
        float x = P[(b * 3 + 0) * NPTS + p0 + p];
        float y = P[(b * 3 + 1) * NPTS + p0 + p];
        float z = P[(b * 3 + 2) * NPTS + p0 + p];
        float geo = fmaf(gwx, x, fmaf(gwy, y, gwz * z)) + bgo;
        O[(size_t)p * NC] = make_float2(geo, acc[p] + bfo);
    }
}

// ---------------------------------------------------------------------------
// knn_fused4 — EXACT r16/r18 kernel (best measured: 106.4us; LDS qt
// delivery). [r23 post-mortem: scalar-pipe readlane delivery was correct but
// SLOWER (114.5us) — v_readlane is VALU-issued, adding ~512 serial ops/wave
// without removing a hidden stall. knn now bracketed by 7 structural
// variants at 106-115us, VALUBusy 66-67% vs ~70us pure-issue floor; residual
// is the lockstep A->T->B->S phase structure + serial S tail.]
// Wave w owns cands [1024w,1024(w+1)); lane owns c[s]=cb[w*1024+s*64+lane].
//  A: full 16-slot dual-chain lane max -> shfl_xor(1,2,4) -> 64 submaxima
//     (128-cand disjoint groups covering all 8192).
//  T: tau = 16th largest of 64 submaxima -> qt_lds[q].w; >=16 witnesses.
//  B: branch-free u16 mask filter (bit-identical fma), ONE ballot/query,
//     packed (lane<<16)|mask entries.
//  S: decode -> idx list (dead mxs row) -> batch-4 gather + u64 insert.
// Grid: NQ/64 = 512 blocks x 512 threads.
// ---------------------------------------------------------------------------
__global__ __launch_bounds__(512, 4) void knn_fused4(
    const float4* __restrict__ cand, const float* __restrict__ xyz,
    int* __restrict__ idxout)
{
    __shared__ float4 qt_lds[64];            // .w = tau after T
    __shared__ float  mxs[64][ILCAP];        // A/T: submaxima; S: idx list
    __shared__ unsigned int  el[8][64][ECAP];
    __shared__ unsigned char ecnt[8][64];

    int tid = threadIdx.x;
    int lane = tid & 63, w = tid >> 6;       // w in 0..7
    int bid = blockIdx.x;
    int b = bid >> 7;                        // 128 blocks per batch
    int qb = (bid & 127) * 64;

    if (tid < 64) {
        int q = qb + tid;
        float x = xyz[(b * 3 + 0) * NPTS + q];
        float y = xyz[(b * 3 + 1) * NPTS + q];
        float z = xyz[(b * 3 + 2) * NPTS + q];
        qt_lds[tid] = make_float4(2.f * x, 2.f * y, 2.f * z, 0.f);
    }

    const float4* cb = cand + b * NPTS;
    int cbase = (w << 10) + lane;            // lane's cands: cbase + s*64
    float4 c[16];
    #pragma unroll
    for (int s = 0; s < 16; s++) c[s] = cb[cbase + (s << 6)];
    // residency force (r15-validated): compiler cannot re-load from memory
    #pragma unroll
    for (int s = 0; s < 16; s++)
        asm volatile("" : "+v"(c[s].x), "+v"(c[s].y), "+v"(c[s].z), "+v"(c[s].w));
    __syncthreads();

    // ---- A: 64 submaxima per query (dual-chain lane max + 8-lane reduce) --
    for (int qi = 0; qi < 64; ++qi) {
        float4 qt = qt_lds[qi];
        float M0 = -3.0e38f, M1 = -3.0e38f;
        #pragma unroll
        for (int s = 0; s < 16; s += 2) {
            float sc0 = fmaf(c[s].x, qt.x, fmaf(c[s].y, qt.y,
                        fmaf(c[s].z, qt.z, -c[s].w)));
            float sc1 = fmaf(c[s+1].x, qt.x, fmaf(c[s+1].y, qt.y,
                        fmaf(c[s+1].z, qt.z, -c[s+1].w)));
            M0 = fmaxf(M0, sc0);
            M1 = fmaxf(M1, sc1);
        }
        float gmx = fmaxf(M0, M1);
        gmx = fmaxf(gmx, __shfl_xor(gmx, 1));
        gmx = fmaxf(gmx, __shfl_xor(gmx, 2));
        gmx = fmaxf(gmx, __shfl_xor(gmx, 4));   // 8-lane group max
        if ((lane & 7) == 0) mxs[qi][(w << 3) + (lane >> 3)] = gmx;
    }
    __syncthreads();

    // ---- T: tau = 16th largest of 64 submaxima -> qt_lds[qq].w ----
    for (int qq = w * 8; qq < w * 8 + 8; ++qq) {
        float v = mxs[qq][lane];
        #pragma unroll
        for (int k = 2; k <= 64; k <<= 1) {
            #pragma unroll
            for (int j = k >> 1; j > 0; j >>= 1) {
                float o = __shfl_xor(v, j);
                bool up = ((lane & k) == 0);
                bool lower = ((lane & j) == 0);
                v = (up == lower) ? fminf(v, o) : fmaxf(v, o);
            }
        }
        float t = __shfl(v, 48);             // 16th largest (all lanes)
        if (lane == 0) qt_lds[qq].w = t;
    }
    __syncthreads();

    // ---- B: branch-free mask filter; ONE ballot per (wave,query) ----
    unsigned long long lmask = (1ull << lane) - 1ull;
    for (int qi = 0; qi < 64; ++qi) {
        float4 qt = qt_lds[qi];              // .w = tau
        unsigned msk = 0;
        #pragma unroll
        for (int s = 0; s < 16; s++) {
            float sc = fmaf(c[s].x, qt.x, fmaf(c[s].y, qt.y,
                       fmaf(c[s].z, qt.z, -c[s].w)));
            msk |= (sc >= qt.w) ? (1u << s) : 0u;
        }
        unsigned long long m = __ballot(msk != 0u);
        if (msk) {
            unsigned pos = (unsigned)__popcll(m & lmask);
            if (pos < ECAP)
                el[w][qi][pos] = ((unsigned)lane << 16) | msk;
        }
        if (lane == 0) {
            unsigned tot = (unsigned)__popcll(m);
            ecnt[w][qi] = (unsigned char)(tot < ECAP ? tot : ECAP);
        }
    }
    __syncthreads();

    // ---- S: decode entries -> idx list (reuse mxs row), then top-16 ----
    if (tid < 64) {
        int qi = tid;
        unsigned* il = (unsigned*)&mxs[qi][0];   // ILCAP u32 slots
        int cnt = 0;
        for (int w2 = 0; w2 < 8; w2++) {
            int cn = ecnt[w2][qi];
            for (int j = 0; j < cn; j++) {
                unsigned e = el[w2][qi][j];
                int base = (w2 << 10) + (int)(e >> 16);
                unsigned mk = e & 0xFFFFu;
                while (mk) {
                    int s = __builtin_ctz(mk);
                    mk &= mk - 1u;
                    if (cnt < ILCAP) il[cnt++] = (unsigned)(base + (s << 6));
                }
            }
        }

        float4 qt = qt_lds[qi];
        unsigned long long s16[KNN];
        #pragma unroll
        for (int j = 0; j < KNN; j++) s16[j] = 0ull;

        for (int j0 = 0; j0 < cnt; j0 += 4) {
            int li[4];
            float4 cd[4];
            #pragma unroll
            for (int t = 0; t < 4; t++) {
                int j = j0 + t;
                li[t] = (j < cnt) ? (int)il[j] : -1;
            }
            #pragma unroll
            for (int t = 0; t < 4; t++)
                if (li[t] >= 0) cd[t] = cb[li[t]];
            #pragma unroll
            for (int t = 0; t < 4; t++) {
                if (li[t] < 0) continue;
                float sc = fmaf(cd[t].x, qt.x, fmaf(cd[t].y, qt.y,
                           fmaf(cd[t].z, qt.z, -cd[t].w)));
                unsigned u = __float_as_uint(sc);
                u ^= (unsigned)((int)u >> 31) | 0x80000000u;
                unsigned long long key =
                    ((unsigned long long)u << 32) | (unsigned)(8191 - li[t]);
                if (key > s16[0]) {
                    bool cj = true;
                    #pragma unroll
                    for (int t2 = 0; t2 < KNN; t2++) {
                        bool cn2 = (t2 < KNN - 1) ? (key > s16[t2 + 1]) : false;
                        unsigned long long fv = cj ? key : s16[t2];
                        s16[t2] = cn2 ? s16[t2 + 1] : fv;
                        cj = cn2;
                    }
                }
            }
        }
        int* op = idxout + (((size_t)(b * NPTS + qb + qi)) << 4);
        #pragma unroll
        for (int j = 0; j < KNN; j++)
            op[j] = 8191 - (int)(s16[j] & 0xFFFFFFFFull);
    }
}

// ---------------------------------------------------------------------------
// fuse — r20 validated: explicit register-batch gathers.
// out[b][o][n] = max_k relu(CF.x + wd*d + GF.x) * relu(CF.y + GF.y)
// ---------------------------------------------------------------------------
__global__ __launch_bounds__(256) void fuse_kernel(
    const float* __restrict__ xyz, const float* __restrict__ Wg,
    const float4* __restrict__ cand, const float2* __restrict__ GF,
    const float2* __restrict__ CF, const int* __restrict__ idxb,
    float* __restrict__ out)
{
    __shared__ float tile[16 * 65];
    int tid = threadIdx.x;
    int o = tid & 63, w = tid >> 6;
    int b = blockIdx.x >> 9;
    int nt = (blockIdx.x & 511) << 4;
    float wd = Wg[o * 10];

    const float4* cb = cand + b * NPTS;
    const float2* gb = GF + (size_t)b * NPTS * NC;

    for (int i = 0; i < 4; i++) {
        int q = nt + w * 4 + i;
        size_t qb = (size_t)(b * NPTS + q);
        float qx = xyz[(b * 3 + 0) * NPTS + q];
        float qy = xyz[(b * 3 + 1) * NPTS + q];
        float qz = xyz[(b * 3 + 2) * NPTS + q];
        float2 cf = CF[qb * NC + o];
        const int* ip = idxb + qb * KNN;

        int mi[16];
        #pragma unroll
        for (int kk = 0; kk < 16; kk++) mi[kk] = ip[kk];   // broadcast loads

        float r = 0.f;
        #pragma unroll
        for (int h = 0; h < 2; h++) {
            float4 cd[8];
            float2 gf[8];
            #pragma unroll
            for (int t = 0; t < 8; t++) cd[t] = cb[mi[h * 8 + t]];
            #pragma unroll
            for (int t = 0; t < 8; t++)
                gf[t] = gb[(size_t)mi[h * 8 + t] * NC + o];
            #pragma unroll
            for (int t = 0; t < 8; t++) {
                float dx = qx - cd[t].x, dy = qy - cd[t].y, dz = qz - cd[t].z;
                float d = sqrtf(fmaf(dx, dx, fmaf(dy, dy, dz * dz)));
                float gpre = cf.x + fmaf(wd, d, gf[t].x);
                float fpre = cf.y + gf[t].y;
                r = fmaxf(r, fmaxf(gpre, 0.f) * fmaxf(fpre, 0.f));
            }
        }
        tile[(w * 4 + i) * 65 + o] = r;
    }
    __syncthreads();
    int row = tid >> 2, cg = (tid & 3) * 4;
    float* orow = out + (size_t)(b * NC + row) * NPTS + nt + cg;
    #pragma unroll
    for (int j = 0; j < 4; j++) orow[j] = tile[(cg + j) * 65 + row];
}

extern "C" void kernel_launch(void* const* d_in, const int* in_sizes, int n_in,
                              void* d_out, int out_size, void* d_ws, size_t ws_size,
                              hipStream_t stream) {
    const float* xyz   = (const float*)d_in[0];
    const float* xyz_s = (const float*)d_in[1];
    const float* fea   = (const float*)d_in[2];
    const float* fea_s = (const float*)d_in[3];
    const float* Wg    = (const float*)d_in[4];
    const float* bg    = (const float*)d_in[5];
    const float* Wf    = (const float*)d_in[6];
    const float* bf    = (const float*)d_in[7];
    float* out = (float*)d_out;

    char* ws = (char*)d_ws;
    float4* cand = (float4*)ws;                 ws += (size_t)NQ * 16;      // 512 KB
    float2* GF   = (float2*)ws;                 ws += (size_t)NQ * NC * 8;  // 16.8 MB
    float2* CF   = (float2*)ws;                 ws += (size_t)NQ * NC * 8;  // 16.8 MB
    int*    idxb = (int*)ws;                                                // 2 MB

    // prep: transposed ownership, 64 points / 64 threads, 2 phases
    prep_kernel<<<(NQ / 64) * 2, 64, 0, stream>>>(
        xyz, xyz_s, fea, fea_s, Wg, bg, Wf, bf, cand, GF, CF);
    knn_fused4<<<NQ / 64, 512, 0, stream>>>(cand, xyz, idxb);
    fuse_kernel<<<NB * (NPTS / 16), 256, 0, stream>>>(
        xyz, Wg, cand, GF, CF, idxb, out);
}